// Round 1
// baseline (1537.050 us; speedup 1.0000x reference)
//
#include <hip/hip_runtime.h>
#include <hip/hip_bf16.h>

// Problem constants
constexpr int Bc = 2, Sc = 2048, Ec = 1024, Hc = 16, Dc = 64;
constexpr int Mrows = Bc * Sc;   // 4096 GEMM rows
constexpr int Kdim  = Ec;        // 1024 reduction dim

// ---------------------------------------------------------------------------
// Kernel 1: Y = quantum(split_heads(x @ W^T)), written as [B,H,S,D] fp32.
// NT GEMM: C[m][n] = sum_k A[m,k] * W[n,k]. Column tile (64) == one head,
// so the cos-cumprod along D is block-local.
// ---------------------------------------------------------------------------
__global__ __launch_bounds__(256) void proj_quantum_kernel(
    const float* __restrict__ A,   // [4096, 1024]
    const float* __restrict__ W,   // [1024, 1024]
    float* __restrict__ out)       // [B,H,S,D]
{
    __shared__ float As[16][65];   // [k][m], +1 pad
    __shared__ float Bs[16][65];   // [k][n]
    __shared__ float Cs[64][65];   // result tile for scan/writeout

    const int tid = threadIdx.x;
    const int tx = tid & 15, ty = tid >> 4;   // 16x16 thread grid
    const int m0 = blockIdx.x * 64;
    const int h  = blockIdx.y;                // head index == column tile
    const int n0 = h * 64;

    const int lr = tid >> 2;           // load row 0..63
    const int lk = (tid & 3) * 4;      // k sub-offset 0,4,8,12

    float acc[4][4] = {};
    for (int k0 = 0; k0 < Kdim; k0 += 16) {
        float4 a4 = *(const float4*)(A + (size_t)(m0 + lr) * Kdim + k0 + lk);
        float4 b4 = *(const float4*)(W + (size_t)(n0 + lr) * Kdim + k0 + lk);
        As[lk + 0][lr] = a4.x; As[lk + 1][lr] = a4.y;
        As[lk + 2][lr] = a4.z; As[lk + 3][lr] = a4.w;
        Bs[lk + 0][lr] = b4.x; Bs[lk + 1][lr] = b4.y;
        Bs[lk + 2][lr] = b4.z; Bs[lk + 3][lr] = b4.w;
        __syncthreads();
        #pragma unroll
        for (int kk = 0; kk < 16; ++kk) {
            float a[4], b[4];
            #pragma unroll
            for (int i = 0; i < 4; ++i) a[i] = As[kk][ty * 4 + i];
            #pragma unroll
            for (int j = 0; j < 4; ++j) b[j] = Bs[kk][tx * 4 + j];
            #pragma unroll
            for (int i = 0; i < 4; ++i)
                #pragma unroll
                for (int j = 0; j < 4; ++j)
                    acc[i][j] = fmaf(a[i], b[j], acc[i][j]);
        }
        __syncthreads();
    }

    // cos into LDS tile
    #pragma unroll
    for (int i = 0; i < 4; ++i)
        #pragma unroll
        for (int j = 0; j < 4; ++j)
            Cs[ty * 4 + i][tx * 4 + j] = __cosf(acc[i][j]);
    __syncthreads();

    // cumprod along the 64 head wires (one thread per row)
    if (tid < 64) {
        float p = 1.0f;
        for (int j = 0; j < 64; ++j) { p *= Cs[tid][j]; Cs[tid][j] = p; }
    }
    __syncthreads();

    // write out to [B,H,S,D]; consecutive tid -> consecutive d (coalesced)
    #pragma unroll
    for (int i = 0; i < 16; ++i) {
        int idx = i * 256 + tid;
        int r = idx >> 6, d = idx & 63;
        int m = m0 + r;
        int b = m >> 11, s = m & (Sc - 1);
        out[(((size_t)b * Hc + h) * Sc + s) * Dc + d] = Cs[r][d];
    }
}

// ---------------------------------------------------------------------------
// Kernel 2: flash attention fp32. Block = (b*H+h, 64-query tile).
// K-tile LDS buffer is reused for P (scores) to fit under 64 KB.
// Writes att as [B,S,E] (transposed heads) for the output GEMM.
// ---------------------------------------------------------------------------
__global__ __launch_bounds__(256) void flash_attn_kernel(
    const float* __restrict__ q, const float* __restrict__ k,
    const float* __restrict__ v, float* __restrict__ att)
{
    __shared__ float Qs[64][65];
    __shared__ float KPs[64][65];   // K tile, reused as P
    __shared__ float Vs[64][65];
    __shared__ float mrow[64], lrow[64], arow[64];

    const int tid = threadIdx.x;
    const int tx = tid & 15, ty = tid >> 4;
    const int bh = blockIdx.x;      // b*H + h
    const int qb = blockIdx.y;      // query tile 0..31

    const float* qp = q + (size_t)bh * Sc * Dc;
    const float* kp = k + (size_t)bh * Sc * Dc;
    const float* vp = v + (size_t)bh * Sc * Dc;

    #pragma unroll
    for (int i = 0; i < 16; ++i) {
        int idx = i * 256 + tid;
        int r = idx >> 6, c = idx & 63;
        Qs[r][c] = qp[(size_t)(qb * 64 + r) * Dc + c];
    }
    if (tid < 64) { mrow[tid] = -3.0e38f; lrow[tid] = 0.0f; }
    float o[4][4] = {};
    __syncthreads();

    for (int kt = 0; kt < Sc / 64; ++kt) {
        #pragma unroll
        for (int i = 0; i < 16; ++i) {
            int idx = i * 256 + tid;
            int r = idx >> 6, c = idx & 63;
            KPs[r][c] = kp[(size_t)(kt * 64 + r) * Dc + c];
            Vs[r][c]  = vp[(size_t)(kt * 64 + r) * Dc + c];
        }
        __syncthreads();

        // scores: 4x4 micro-tile per thread, S[r][c] = dot(Q[r], K[c]) / 8
        float s[4][4] = {};
        #pragma unroll 8
        for (int d = 0; d < 64; ++d) {
            float a[4], b[4];
            #pragma unroll
            for (int i = 0; i < 4; ++i) a[i] = Qs[ty * 4 + i][d];
            #pragma unroll
            for (int j = 0; j < 4; ++j) b[j] = KPs[tx * 4 + j][d];
            #pragma unroll
            for (int i = 0; i < 4; ++i)
                #pragma unroll
                for (int j = 0; j < 4; ++j)
                    s[i][j] = fmaf(a[i], b[j], s[i][j]);
        }
        __syncthreads();   // everyone done reading K before overwrite as P
        #pragma unroll
        for (int i = 0; i < 4; ++i)
            #pragma unroll
            for (int j = 0; j < 4; ++j)
                KPs[ty * 4 + i][tx * 4 + j] = s[i][j] * 0.125f;
        __syncthreads();

        // online softmax row pass (one thread per query row)
        if (tid < 64) {
            float mold = mrow[tid];
            float mx = mold;
            for (int c = 0; c < 64; ++c) mx = fmaxf(mx, KPs[tid][c]);
            float alpha = __expf(mold - mx);
            float sum = 0.0f;
            for (int c = 0; c < 64; ++c) {
                float p = __expf(KPs[tid][c] - mx);
                KPs[tid][c] = p;
                sum += p;
            }
            lrow[tid] = lrow[tid] * alpha + sum;
            mrow[tid] = mx;
            arow[tid] = alpha;
        }
        __syncthreads();

        // O = O*alpha + P @ V
        float al[4];
        #pragma unroll
        for (int i = 0; i < 4; ++i) al[i] = arow[ty * 4 + i];
        #pragma unroll
        for (int i = 0; i < 4; ++i)
            #pragma unroll
            for (int j = 0; j < 4; ++j)
                o[i][j] *= al[i];
        #pragma unroll 8
        for (int c = 0; c < 64; ++c) {
            float p[4], vv[4];
            #pragma unroll
            for (int i = 0; i < 4; ++i) p[i] = KPs[ty * 4 + i][c];
            #pragma unroll
            for (int j = 0; j < 4; ++j) vv[j] = Vs[c][tx * 4 + j];
            #pragma unroll
            for (int i = 0; i < 4; ++i)
                #pragma unroll
                for (int j = 0; j < 4; ++j)
                    o[i][j] = fmaf(p[i], vv[j], o[i][j]);
        }
        __syncthreads();   // before next tile overwrites KPs/Vs
    }

    // finalize + write att[b][s][h*64 + d]
    const int b = bh >> 4, h = bh & 15;
    #pragma unroll
    for (int i = 0; i < 4; ++i) {
        float inv = 1.0f / lrow[ty * 4 + i];
        int srow = qb * 64 + ty * 4 + i;
        float4 o4 = make_float4(o[i][0] * inv, o[i][1] * inv,
                                o[i][2] * inv, o[i][3] * inv);
        *(float4*)(att + ((size_t)b * Sc + srow) * Ec + h * 64 + tx * 4) = o4;
    }
}

// ---------------------------------------------------------------------------
// Kernel 3: out = att @ Wc^T + bc  (same NT GEMM, bias epilogue)
// ---------------------------------------------------------------------------
__global__ __launch_bounds__(256) void out_proj_kernel(
    const float* __restrict__ A,     // [4096, 1024] (att)
    const float* __restrict__ W,     // [1024, 1024] (Wc)
    const float* __restrict__ bias,  // [1024]
    float* __restrict__ out)         // [4096, 1024]
{
    __shared__ float As[16][65];
    __shared__ float Bs[16][65];

    const int tid = threadIdx.x;
    const int tx = tid & 15, ty = tid >> 4;
    const int m0 = blockIdx.x * 64;
    const int n0 = blockIdx.y * 64;

    const int lr = tid >> 2;
    const int lk = (tid & 3) * 4;

    float acc[4][4] = {};
    for (int k0 = 0; k0 < Kdim; k0 += 16) {
        float4 a4 = *(const float4*)(A + (size_t)(m0 + lr) * Kdim + k0 + lk);
        float4 b4 = *(const float4*)(W + (size_t)(n0 + lr) * Kdim + k0 + lk);
        As[lk + 0][lr] = a4.x; As[lk + 1][lr] = a4.y;
        As[lk + 2][lr] = a4.z; As[lk + 3][lr] = a4.w;
        Bs[lk + 0][lr] = b4.x; Bs[lk + 1][lr] = b4.y;
        Bs[lk + 2][lr] = b4.z; Bs[lk + 3][lr] = b4.w;
        __syncthreads();
        #pragma unroll
        for (int kk = 0; kk < 16; ++kk) {
            float a[4], b[4];
            #pragma unroll
            for (int i = 0; i < 4; ++i) a[i] = As[kk][ty * 4 + i];
            #pragma unroll
            for (int j = 0; j < 4; ++j) b[j] = Bs[kk][tx * 4 + j];
            #pragma unroll
            for (int i = 0; i < 4; ++i)
                #pragma unroll
                for (int j = 0; j < 4; ++j)
                    acc[i][j] = fmaf(a[i], b[j], acc[i][j]);
        }
        __syncthreads();
    }

    float4 bv = *(const float4*)(bias + n0 + tx * 4);
    #pragma unroll
    for (int i = 0; i < 4; ++i) {
        int m = m0 + ty * 4 + i;
        float4 o4 = make_float4(acc[i][0] + bv.x, acc[i][1] + bv.y,
                                acc[i][2] + bv.z, acc[i][3] + bv.w);
        *(float4*)(out + (size_t)m * Kdim + n0 + tx * 4) = o4;
    }
}

// ---------------------------------------------------------------------------
extern "C" void kernel_launch(void* const* d_in, const int* in_sizes, int n_in,
                              void* d_out, int out_size, void* d_ws, size_t ws_size,
                              hipStream_t stream) {
    const float* x  = (const float*)d_in[0];
    const float* Wq = (const float*)d_in[1];
    const float* Wk = (const float*)d_in[2];
    const float* Wv = (const float*)d_in[3];
    const float* Wc = (const float*)d_in[4];
    const float* bc = (const float*)d_in[5];
    float* out = (float*)d_out;

    // workspace: q,k,v [B,H,S,D] + att [B,S,E], all fp32 (64 MB total)
    const size_t tensor_elems = (size_t)Bc * Hc * Sc * Dc;   // 4M
    float* qws = (float*)d_ws;
    float* kws = qws + tensor_elems;
    float* vws = kws + tensor_elems;
    float* aws = vws + tensor_elems;

    dim3 gblk(256);
    dim3 ggemm(Mrows / 64, Ec / 64);          // (64, 16)
    hipLaunchKernelGGL(proj_quantum_kernel, ggemm, gblk, 0, stream, x, Wq, qws);
    hipLaunchKernelGGL(proj_quantum_kernel, ggemm, gblk, 0, stream, x, Wk, kws);
    hipLaunchKernelGGL(proj_quantum_kernel, ggemm, gblk, 0, stream, x, Wv, vws);

    dim3 gattn(Bc * Hc, Sc / 64);             // (32, 32)
    hipLaunchKernelGGL(flash_attn_kernel, gattn, gblk, 0, stream, qws, kws, vws, aws);

    hipLaunchKernelGGL(out_proj_kernel, ggemm, gblk, 0, stream, aws, Wc, bc, out);
}

// Round 2
// 251.520 us; speedup vs baseline: 6.1110x; 6.1110x over previous
//
#include <hip/hip_runtime.h>
#include <hip/hip_bf16.h>

// Problem constants
constexpr int Bc = 2, Sc = 2048, Ec = 1024, Hc = 16, Dc = 64;
constexpr int Mrows = Bc * Sc;   // 4096
constexpr int Kdim  = Ec;        // 1024

typedef float  floatx4 __attribute__((ext_vector_type(4)));
typedef short  shortx8 __attribute__((ext_vector_type(8)));

__device__ inline unsigned short f2bf(float f) {
    union { __hip_bfloat16 h; unsigned short u; } cv;
    cv.h = __float2bfloat16(f);
    return cv.u;
}

// ---------------------------------------------------------------------------
// Kernel 0: convert x, Wq, Wk, Wv, Wc (fp32) -> bf16 workspace
// x: 4 Mi elems; each W: 1 Mi elems. 4 elems/thread.
// ---------------------------------------------------------------------------
__global__ __launch_bounds__(256) void convert_all_kernel(
    const float* __restrict__ x,  const float* __restrict__ Wq,
    const float* __restrict__ Wk, const float* __restrict__ Wv,
    const float* __restrict__ Wc,
    unsigned short* __restrict__ xb,  unsigned short* __restrict__ Wqb,
    unsigned short* __restrict__ Wkb, unsigned short* __restrict__ Wvb,
    unsigned short* __restrict__ Wcb)
{
    const long t = (long)blockIdx.x * 256 + threadIdx.x;
    const long i = t * 4;
    const float* src; unsigned short* dst; long off;
    if (i < 4194304) { src = x; dst = xb; off = i; }
    else {
        long j = i - 4194304;
        int wsel = (int)(j >> 20);
        off = j & 1048575;
        src = (wsel == 0) ? Wq : (wsel == 1) ? Wk : (wsel == 2) ? Wv : Wc;
        dst = (wsel == 0) ? Wqb : (wsel == 1) ? Wkb : (wsel == 2) ? Wvb : Wcb;
    }
    float4 v = *(const float4*)(src + off);
    unsigned short tmp[4] __attribute__((aligned(8)));
    tmp[0] = f2bf(v.x); tmp[1] = f2bf(v.y); tmp[2] = f2bf(v.z); tmp[3] = f2bf(v.w);
    *(uint2*)(dst + off) = *(uint2*)tmp;
}

// ---------------------------------------------------------------------------
// Kernel 1: MFMA projection + quantum epilogue.
// C[m][n] = sum_k A[m][k]*W[n][k] (NT). 64x64 tile, BK=64, 4 waves.
// Wave w owns M rows [16w,16w+16), all 4 N-subtiles.
// Epilogue: cos -> row-wise cumprod over the 64 head wires (segmented scan).
// MODE 0: write [B,H,S,D] bf16 (q,k).  MODE 1: write [B,H,D,S] bf16 (v^T).
// ---------------------------------------------------------------------------
template<int MODE>
__global__ __launch_bounds__(256) void proj_mfma_kernel(
    const unsigned short* __restrict__ Ab,   // [4096,1024] bf16
    const unsigned short* __restrict__ Wb,   // [1024,1024] bf16
    unsigned short* __restrict__ out)
{
    __shared__ __align__(16) unsigned short As[64][72];  // stride 72: uniform banks
    __shared__ __align__(16) unsigned short Ws[64][72];
    __shared__ __align__(16) float Cs[64][68];           // fp32 tile for scan
    __shared__ float Sp[64][5];

    const int tid  = threadIdx.x;
    const int w    = tid >> 6;
    const int l15  = tid & 15;
    const int quad = (tid >> 4) & 3;
    const int m0   = blockIdx.x * 64;
    const int h    = blockIdx.y;
    const int n0   = h * 64;

    const int srow = tid >> 3;   // 0..31
    const int schk = tid & 7;    // 16B chunk within 128B row

    floatx4 acc[4];
    #pragma unroll
    for (int nt = 0; nt < 4; ++nt)
        #pragma unroll
        for (int e = 0; e < 4; ++e) acc[nt][e] = 0.0f;

    for (int k0 = 0; k0 < Kdim; k0 += 64) {
        #pragma unroll
        for (int it = 0; it < 2; ++it) {
            int row = srow + it * 32;
            *(shortx8*)&As[row][schk * 8] =
                *(const shortx8*)(Ab + (size_t)(m0 + row) * Kdim + k0 + schk * 8);
            *(shortx8*)&Ws[row][schk * 8] =
                *(const shortx8*)(Wb + (size_t)(n0 + row) * Kdim + k0 + schk * 8);
        }
        __syncthreads();
        #pragma unroll
        for (int ks = 0; ks < 2; ++ks) {
            shortx8 af = *(shortx8*)&As[16 * w + l15][32 * ks + 8 * quad];
            #pragma unroll
            for (int nt = 0; nt < 4; ++nt) {
                shortx8 bf = *(shortx8*)&Ws[16 * nt + l15][32 * ks + 8 * quad];
                acc[nt] = __builtin_amdgcn_mfma_f32_16x16x32_bf16(af, bf, acc[nt], 0, 0, 0);
            }
        }
        __syncthreads();
    }

    // cos into Cs (C-layout: row = 16w + 4*quad + r, col = 16*nt + l15)
    #pragma unroll
    for (int nt = 0; nt < 4; ++nt)
        #pragma unroll
        for (int r = 0; r < 4; ++r)
            Cs[16 * w + 4 * quad + r][16 * nt + l15] = __cosf(acc[nt][r]);
    __syncthreads();

    // segmented cumprod along the 64 cols: 4 segments of 16, all 256 threads busy
    {
        const int row = tid >> 2, seg = tid & 3;
        float4 v[4];
        #pragma unroll
        for (int j = 0; j < 4; ++j)
            v[j] = *(float4*)&Cs[row][seg * 16 + j * 4];
        float pr = 1.0f;
        #pragma unroll
        for (int j = 0; j < 4; ++j) pr *= v[j].x * v[j].y * v[j].z * v[j].w;
        Sp[row][seg] = pr;
        __syncthreads();
        float p = 1.0f;
        for (int j = 0; j < seg; ++j) p *= Sp[row][j];
        float* vf = (float*)v;
        #pragma unroll
        for (int c = 0; c < 16; ++c) { p *= vf[c]; Cs[row][seg * 16 + c] = p; }
    }
    __syncthreads();

    const int b    = m0 >> 11;
    const int mloc = m0 & (Sc - 1);
    if (MODE == 0) {
        // out[b][h][s][d], thread: row, 16-col chunk
        const int row = tid >> 2, chk = tid & 3;
        const int s = mloc + row;
        unsigned short tmp[16] __attribute__((aligned(16)));
        #pragma unroll
        for (int c = 0; c < 16; ++c) tmp[c] = f2bf(Cs[row][chk * 16 + c]);
        size_t base = (((size_t)b * Hc + h) * Sc + s) * Dc + chk * 16;
        *(shortx8*)(out + base)     = *(shortx8*)&tmp[0];
        *(shortx8*)(out + base + 8) = *(shortx8*)&tmp[8];
    } else {
        // out[b][h][d][s] (transposed): thread: d, 16-s chunk
        const int d = tid >> 2, chk = tid & 3;
        unsigned short tmp[16] __attribute__((aligned(16)));
        #pragma unroll
        for (int c = 0; c < 16; ++c) tmp[c] = f2bf(Cs[chk * 16 + c][d]);
        size_t base = (((size_t)b * Hc + h) * Dc + d) * Sc + mloc + chk * 16;
        *(shortx8*)(out + base)     = *(shortx8*)&tmp[0];
        *(shortx8*)(out + base + 8) = *(shortx8*)&tmp[8];
    }
}

// ---------------------------------------------------------------------------
// Kernel 2: MFMA flash attention.
// Block = (qb, bh): 64 query rows. Wave w owns q cols [16w,16w+16).
// ST = K·Q^T  (M=s, N=q, k=d): softmax state (m,l,alpha) become LANE SCALARS.
// P^T round-trips through wave-private LDS (Pq[q][s]) into B-operand layout.
// O^T = V^T·P^T accumulated in registers; V supplied pre-transposed [B,H,D,S].
// Writes att[B,S,E] bf16.
// ---------------------------------------------------------------------------
__global__ __launch_bounds__(256) void attn_mfma_kernel(
    const unsigned short* __restrict__ qg,   // [B,H,S,D]
    const unsigned short* __restrict__ kg,   // [B,H,S,D]
    const unsigned short* __restrict__ vtg,  // [B,H,D,S]
    unsigned short* __restrict__ att)        // [B,S,E]
{
    __shared__ __align__(16) unsigned short Ks[64][72];
    __shared__ __align__(16) unsigned short VTs[64][72];
    __shared__ __align__(16) unsigned short Pq[64][72];

    const int tid  = threadIdx.x;
    const int w    = tid >> 6;
    const int l15  = tid & 15;
    const int quad = (tid >> 4) & 3;
    const int qb   = blockIdx.x;   // fastest-varying: same bh adjacent for L2
    const int bh   = blockIdx.y;

    const unsigned short* qp = qg  + (size_t)bh * Sc * Dc;
    const unsigned short* kp = kg  + (size_t)bh * Sc * Dc;
    const unsigned short* vp = vtg + (size_t)bh * Dc * Sc;

    // Q B-operand fragments: lane reads Q[q=16w+l15][d=32ks+8quad..+7] (16B)
    const int qrow = qb * 64 + 16 * w + l15;
    shortx8 qf[2];
    qf[0] = *(const shortx8*)(qp + (size_t)qrow * Dc + 8 * quad);
    qf[1] = *(const shortx8*)(qp + (size_t)qrow * Dc + 32 + 8 * quad);

    floatx4 Oacc[4];
    #pragma unroll
    for (int mt = 0; mt < 4; ++mt)
        #pragma unroll
        for (int e = 0; e < 4; ++e) Oacc[mt][e] = 0.0f;
    float mrun = -INFINITY, lrun = 0.0f;

    const int srow = tid >> 3, schk = tid & 7;

    for (int kt = 0; kt < Sc / 64; ++kt) {
        #pragma unroll
        for (int it = 0; it < 2; ++it) {
            int row = srow + 32 * it;
            *(shortx8*)&Ks[row][schk * 8] =
                *(const shortx8*)(kp + (size_t)(kt * 64 + row) * Dc + schk * 8);
            *(shortx8*)&VTs[row][schk * 8] =
                *(const shortx8*)(vp + (size_t)row * Sc + kt * 64 + schk * 8);
        }
        __syncthreads();

        // ST = K·Q^T : lane holds ST[s=16mt+4quad+r][q=16w+l15]
        floatx4 st[4];
        #pragma unroll
        for (int mt = 0; mt < 4; ++mt)
            #pragma unroll
            for (int e = 0; e < 4; ++e) st[mt][e] = 0.0f;
        #pragma unroll
        for (int ks = 0; ks < 2; ++ks)
            #pragma unroll
            for (int mt = 0; mt < 4; ++mt) {
                shortx8 kf = *(shortx8*)&Ks[16 * mt + l15][32 * ks + 8 * quad];
                st[mt] = __builtin_amdgcn_mfma_f32_16x16x32_bf16(kf, qf[ks], st[mt], 0, 0, 0);
            }

        // online softmax over s (per q column): reduce across the 4 quads
        float vmax = -INFINITY;
        #pragma unroll
        for (int mt = 0; mt < 4; ++mt)
            #pragma unroll
            for (int r = 0; r < 4; ++r) {
                float sv = st[mt][r] * 0.125f;
                st[mt][r] = sv;
                vmax = fmaxf(vmax, sv);
            }
        vmax = fmaxf(vmax, __shfl_xor(vmax, 16, 64));
        vmax = fmaxf(vmax, __shfl_xor(vmax, 32, 64));
        const float mnew  = fmaxf(mrun, vmax);
        const float alpha = __expf(mrun - mnew);
        float rsum = 0.0f;
        #pragma unroll
        for (int mt = 0; mt < 4; ++mt) {
            float p0 = __expf(st[mt][0] - mnew);
            float p1 = __expf(st[mt][1] - mnew);
            float p2 = __expf(st[mt][2] - mnew);
            float p3 = __expf(st[mt][3] - mnew);
            rsum += (p0 + p1) + (p2 + p3);
            unsigned short tmp[4] __attribute__((aligned(8)));
            tmp[0] = f2bf(p0); tmp[1] = f2bf(p1); tmp[2] = f2bf(p2); tmp[3] = f2bf(p3);
            // Pq[q][s]: s = 16mt + 4quad + r (wave-private rows: q in [16w,16w+16))
            *(uint2*)&Pq[16 * w + l15][16 * mt + 4 * quad] = *(uint2*)tmp;
        }
        rsum += __shfl_xor(rsum, 16, 64);
        rsum += __shfl_xor(rsum, 32, 64);
        lrun = lrun * alpha + rsum;
        mrun = mnew;
        #pragma unroll
        for (int mt = 0; mt < 4; ++mt)
            #pragma unroll
            for (int e = 0; e < 4; ++e) Oacc[mt][e] *= alpha;

        // O^T += V^T · P^T : A = VT frag, B = Pq frag (wave-private read)
        #pragma unroll
        for (int ks = 0; ks < 2; ++ks) {
            shortx8 pf = *(shortx8*)&Pq[16 * w + l15][32 * ks + 8 * quad];
            #pragma unroll
            for (int mt = 0; mt < 4; ++mt) {
                shortx8 vf = *(shortx8*)&VTs[16 * mt + l15][32 * ks + 8 * quad];
                Oacc[mt] = __builtin_amdgcn_mfma_f32_16x16x32_bf16(vf, pf, Oacc[mt], 0, 0, 0);
            }
        }
        __syncthreads();
    }

    // finalize: lane holds O^T[d=16mt+4quad+r][q=qrow]; store 4 bf16 (8B) per mt
    const float inv = 1.0f / lrun;
    const int b = bh >> 4, hh = bh & 15;
    #pragma unroll
    for (int mt = 0; mt < 4; ++mt) {
        unsigned short tmp[4] __attribute__((aligned(8)));
        #pragma unroll
        for (int r = 0; r < 4; ++r) tmp[r] = f2bf(Oacc[mt][r] * inv);
        size_t base = ((size_t)b * Sc + qrow) * Ec + hh * 64 + 16 * mt + 4 * quad;
        *(uint2*)(att + base) = *(uint2*)tmp;
    }
}

// ---------------------------------------------------------------------------
// Kernel 3: MFMA out-projection, out = att @ Wc^T + bc (fp32 out)
// ---------------------------------------------------------------------------
__global__ __launch_bounds__(256) void outproj_mfma_kernel(
    const unsigned short* __restrict__ Ab,   // attb [4096,1024] bf16
    const unsigned short* __restrict__ Wb,   // Wcb [1024,1024] bf16
    const float* __restrict__ bias,
    float* __restrict__ out)                 // [4096,1024] fp32
{
    __shared__ __align__(16) unsigned short As[64][72];
    __shared__ __align__(16) unsigned short Ws[64][72];

    const int tid  = threadIdx.x;
    const int w    = tid >> 6;
    const int l15  = tid & 15;
    const int quad = (tid >> 4) & 3;
    const int m0   = blockIdx.x * 64;
    const int n0   = blockIdx.y * 64;

    const int srow = tid >> 3, schk = tid & 7;

    floatx4 acc[4];
    #pragma unroll
    for (int nt = 0; nt < 4; ++nt)
        #pragma unroll
        for (int e = 0; e < 4; ++e) acc[nt][e] = 0.0f;

    for (int k0 = 0; k0 < Kdim; k0 += 64) {
        #pragma unroll
        for (int it = 0; it < 2; ++it) {
            int row = srow + it * 32;
            *(shortx8*)&As[row][schk * 8] =
                *(const shortx8*)(Ab + (size_t)(m0 + row) * Kdim + k0 + schk * 8);
            *(shortx8*)&Ws[row][schk * 8] =
                *(const shortx8*)(Wb + (size_t)(n0 + row) * Kdim + k0 + schk * 8);
        }
        __syncthreads();
        #pragma unroll
        for (int ks = 0; ks < 2; ++ks) {
            shortx8 af = *(shortx8*)&As[16 * w + l15][32 * ks + 8 * quad];
            #pragma unroll
            for (int nt = 0; nt < 4; ++nt) {
                shortx8 bf = *(shortx8*)&Ws[16 * nt + l15][32 * ks + 8 * quad];
                acc[nt] = __builtin_amdgcn_mfma_f32_16x16x32_bf16(af, bf, acc[nt], 0, 0, 0);
            }
        }
        __syncthreads();
    }

    #pragma unroll
    for (int nt = 0; nt < 4; ++nt) {
        const float bv = bias[n0 + 16 * nt + l15];
        #pragma unroll
        for (int r = 0; r < 4; ++r) {
            int m = m0 + 16 * w + 4 * quad + r;
            out[(size_t)m * Kdim + n0 + 16 * nt + l15] = acc[nt][r] + bv;
        }
    }
}

// ---------------------------------------------------------------------------
extern "C" void kernel_launch(void* const* d_in, const int* in_sizes, int n_in,
                              void* d_out, int out_size, void* d_ws, size_t ws_size,
                              hipStream_t stream) {
    const float* x  = (const float*)d_in[0];
    const float* Wq = (const float*)d_in[1];
    const float* Wk = (const float*)d_in[2];
    const float* Wv = (const float*)d_in[3];
    const float* Wc = (const float*)d_in[4];
    const float* bc = (const float*)d_in[5];
    float* out = (float*)d_out;

    // bf16 workspace layout (bytes): xb 8M | Wqb/Wkb/Wvb/Wcb 2M ea | qb,kb 8M ea
    // | vtb 8M | attb 8M  => 48 MB total
    char* p = (char*)d_ws;
    unsigned short* xb   = (unsigned short*)(p);
    unsigned short* Wqb  = (unsigned short*)(p + (8u << 20));
    unsigned short* Wkb  = (unsigned short*)(p + (10u << 20));
    unsigned short* Wvb  = (unsigned short*)(p + (12u << 20));
    unsigned short* Wcb  = (unsigned short*)(p + (14u << 20));
    unsigned short* qb_  = (unsigned short*)(p + (16u << 20));
    unsigned short* kb_  = (unsigned short*)(p + (24u << 20));
    unsigned short* vtb  = (unsigned short*)(p + (32u << 20));
    unsigned short* attb = (unsigned short*)(p + (40u << 20));

    hipLaunchKernelGGL(convert_all_kernel, dim3(8192), dim3(256), 0, stream,
                       x, Wq, Wk, Wv, Wc, xb, Wqb, Wkb, Wvb, Wcb);

    dim3 gproj(Mrows / 64, Hc);   // (64, 16)
    hipLaunchKernelGGL((proj_mfma_kernel<0>), gproj, dim3(256), 0, stream, xb, Wqb, qb_);
    hipLaunchKernelGGL((proj_mfma_kernel<0>), gproj, dim3(256), 0, stream, xb, Wkb, kb_);
    hipLaunchKernelGGL((proj_mfma_kernel<1>), gproj, dim3(256), 0, stream, xb, Wvb, vtb);

    hipLaunchKernelGGL(attn_mfma_kernel, dim3(Sc / 64, Bc * Hc), dim3(256), 0, stream,
                       qb_, kb_, vtb, attb);

    hipLaunchKernelGGL(outproj_mfma_kernel, dim3(Mrows / 64, Ec / 64), dim3(256), 0, stream,
                       attb, Wcb, bc, out);
}

// Round 3
// 228.575 us; speedup vs baseline: 6.7245x; 1.1004x over previous
//
#include <hip/hip_runtime.h>
#include <hip/hip_bf16.h>

// Problem constants
constexpr int Bc = 2, Sc = 2048, Ec = 1024, Hc = 16, Dc = 64;
constexpr int Mrows = Bc * Sc;   // 4096
constexpr int Kdim  = Ec;        // 1024

typedef float  floatx4 __attribute__((ext_vector_type(4)));
typedef short  shortx8 __attribute__((ext_vector_type(8)));

__device__ inline unsigned short f2bf(float f) {
    union { __hip_bfloat16 h; unsigned short u; } cv;
    cv.h = __float2bfloat16(f);
    return cv.u;
}

__device__ inline float exp2_fast(float x) {
#if __has_builtin(__builtin_amdgcn_exp2f)
    return __builtin_amdgcn_exp2f(x);
#else
    return __expf(x * 0.69314718056f);   // e^(x ln2) = 2^x
#endif
}

// ---------------------------------------------------------------------------
// Kernel 0: convert x, Wq, Wk, Wv, Wc (fp32) -> bf16 workspace
// ---------------------------------------------------------------------------
__global__ __launch_bounds__(256) void convert_all_kernel(
    const float* __restrict__ x,  const float* __restrict__ Wq,
    const float* __restrict__ Wk, const float* __restrict__ Wv,
    const float* __restrict__ Wc,
    unsigned short* __restrict__ xb,  unsigned short* __restrict__ Wqb,
    unsigned short* __restrict__ Wkb, unsigned short* __restrict__ Wvb,
    unsigned short* __restrict__ Wcb)
{
    const long t = (long)blockIdx.x * 256 + threadIdx.x;
    const long i = t * 4;
    const float* src; unsigned short* dst; long off;
    if (i < 4194304) { src = x; dst = xb; off = i; }
    else {
        long j = i - 4194304;
        int wsel = (int)(j >> 20);
        off = j & 1048575;
        src = (wsel == 0) ? Wq : (wsel == 1) ? Wk : (wsel == 2) ? Wv : Wc;
        dst = (wsel == 0) ? Wqb : (wsel == 1) ? Wkb : (wsel == 2) ? Wvb : Wcb;
    }
    float4 v = *(const float4*)(src + off);
    unsigned short tmp[4] __attribute__((aligned(8)));
    tmp[0] = f2bf(v.x); tmp[1] = f2bf(v.y); tmp[2] = f2bf(v.z); tmp[3] = f2bf(v.w);
    *(uint2*)(dst + off) = *(uint2*)tmp;
}

// ---------------------------------------------------------------------------
// Kernel 1: MFMA projection + quantum epilogue, 128x128 tile (2 heads/block).
// blockIdx.z selects {q,k,v}; z==2 (v) writes transposed [B,H,D,S].
// 4 waves in 2x2 quadrants (64m x 64n each). Epilogue: cos -> per-head
// 64-wire cumprod, two 64-row passes through a Cs buffer that unions As/Ws.
// ---------------------------------------------------------------------------
__global__ __launch_bounds__(256) void proj_mfma_kernel(
    const unsigned short* __restrict__ Ab,   // x bf16 [4096,1024]
    const unsigned short* __restrict__ Wqb,
    const unsigned short* __restrict__ Wkb,
    const unsigned short* __restrict__ Wvb,
    unsigned short* __restrict__ oq,         // [B,H,S,D]
    unsigned short* __restrict__ ok,         // [B,H,S,D]
    unsigned short* __restrict__ ov)         // [B,H,D,S] (transposed)
{
    __shared__ __align__(16) char smem[128 * 72 * 2 * 2];   // 36864 B
    unsigned short (*As)[72] = (unsigned short(*)[72])smem;
    unsigned short (*Ws)[72] = (unsigned short(*)[72])(smem + 128 * 72 * 2);
    float (*Cs)[132] = (float(*)[132])smem;                 // 64*132*4 = 33792 B
    __shared__ float Sp[64][9];

    const int z = blockIdx.z;
    const unsigned short* Wb = (z == 0) ? Wqb : (z == 1) ? Wkb : Wvb;
    unsigned short* out      = (z == 0) ? oq  : (z == 1) ? ok  : ov;
    const int mode = (z == 2) ? 1 : 0;

    const int tid = threadIdx.x;
    const int w = tid >> 6, l15 = tid & 15, quad = (tid >> 4) & 3;
    const int wq = w >> 1, wn = w & 1;
    const int m0 = blockIdx.x * 128;
    const int n0 = blockIdx.y * 128;
    const int h0 = n0 >> 6;
    const int srow = tid >> 3, schk = tid & 7;

    floatx4 acc[4][4];
    #pragma unroll
    for (int ms = 0; ms < 4; ++ms)
        #pragma unroll
        for (int ns = 0; ns < 4; ++ns)
            #pragma unroll
            for (int e = 0; e < 4; ++e) acc[ms][ns][e] = 0.0f;

    for (int k0 = 0; k0 < Kdim; k0 += 64) {
        #pragma unroll
        for (int it = 0; it < 4; ++it) {
            int row = srow + 32 * it;
            *(shortx8*)&As[row][schk * 8] =
                *(const shortx8*)(Ab + (size_t)(m0 + row) * Kdim + k0 + schk * 8);
            *(shortx8*)&Ws[row][schk * 8] =
                *(const shortx8*)(Wb + (size_t)(n0 + row) * Kdim + k0 + schk * 8);
        }
        __syncthreads();
        #pragma unroll
        for (int ks = 0; ks < 2; ++ks) {
            shortx8 af[4], bf[4];
            #pragma unroll
            for (int ms = 0; ms < 4; ++ms)
                af[ms] = *(shortx8*)&As[64 * wq + 16 * ms + l15][32 * ks + 8 * quad];
            #pragma unroll
            for (int ns = 0; ns < 4; ++ns)
                bf[ns] = *(shortx8*)&Ws[64 * wn + 16 * ns + l15][32 * ks + 8 * quad];
            #pragma unroll
            for (int ms = 0; ms < 4; ++ms)
                #pragma unroll
                for (int ns = 0; ns < 4; ++ns)
                    acc[ms][ns] = __builtin_amdgcn_mfma_f32_16x16x32_bf16(
                        af[ms], bf[ns], acc[ms][ns], 0, 0, 0);
        }
        __syncthreads();
    }

    const int b = m0 >> 11;
    const int sbase = m0 & (Sc - 1);

    // Epilogue: two 64-row passes (Cs overlays As/Ws; K-loop is done).
    for (int pass = 0; pass < 2; ++pass) {
        if (wq == pass) {
            #pragma unroll
            for (int ms = 0; ms < 4; ++ms)
                #pragma unroll
                for (int ns = 0; ns < 4; ++ns)
                    #pragma unroll
                    for (int r = 0; r < 4; ++r)
                        Cs[16 * ms + 4 * quad + r][64 * wn + 16 * ns + l15] =
                            __cosf(acc[ms][ns][r]);
        }
        __syncthreads();
        // segment products: 64 rows x 8 segments of 16
        #pragma unroll
        for (int t = tid; t < 512; t += 256) {
            int row = t >> 3, seg = t & 7;
            float pr = 1.0f;
            #pragma unroll
            for (int c = 0; c < 16; ++c) pr *= Cs[row][seg * 16 + c];
            Sp[row][seg] = pr;
        }
        __syncthreads();
        if (mode == 0) {
            #pragma unroll
            for (int t = tid; t < 512; t += 256) {
                int row = t >> 3, seg = t & 7;
                float p = 1.0f;
                for (int j = (seg & 4); j < seg; ++j) p *= Sp[row][j];
                unsigned short tmp[16] __attribute__((aligned(16)));
                #pragma unroll
                for (int c = 0; c < 16; ++c) { p *= Cs[row][seg * 16 + c]; tmp[c] = f2bf(p); }
                int h = h0 + (seg >> 2);
                int s = sbase + pass * 64 + row;
                size_t base = (((size_t)b * Hc + h) * Sc + s) * Dc + (seg & 3) * 16;
                *(shortx8*)(out + base)     = *(shortx8*)&tmp[0];
                *(shortx8*)(out + base + 8) = *(shortx8*)&tmp[8];
            }
            __syncthreads();
        } else {
            // cumprod in place, then transposed write [B,H,D,S]
            #pragma unroll
            for (int t = tid; t < 512; t += 256) {
                int row = t >> 3, seg = t & 7;
                float p = 1.0f;
                for (int j = (seg & 4); j < seg; ++j) p *= Sp[row][j];
                #pragma unroll
                for (int c = 0; c < 16; ++c) { p *= Cs[row][seg * 16 + c]; Cs[row][seg * 16 + c] = p; }
            }
            __syncthreads();
            #pragma unroll
            for (int t = tid; t < 512; t += 256) {
                int col = t >> 2, chunk = t & 3;     // col 0..127, chunk 0..3
                int h = h0 + (col >> 6), d = col & 63;
                unsigned short tmp[16] __attribute__((aligned(16)));
                #pragma unroll
                for (int j = 0; j < 16; ++j) tmp[j] = f2bf(Cs[chunk * 16 + j][col]);
                size_t base = (((size_t)b * Hc + h) * Dc + d) * Sc
                              + sbase + pass * 64 + chunk * 16;
                *(shortx8*)(out + base)     = *(shortx8*)&tmp[0];
                *(shortx8*)(out + base + 8) = *(shortx8*)&tmp[8];
            }
            __syncthreads();
        }
    }
}

// ---------------------------------------------------------------------------
// Kernel 2: MFMA flash attention, QTILE=128, fixed-max softmax.
// Scores are bounded (|q|,|k|<=1 -> |s|<=8), so exp(s) needs no max
// subtraction: no running max, no alpha rescale, l-sum reduced once at end.
// Wave w owns q rows [32w,32w+32) as two 16-row subtiles; kf/vf fragments
// are hoisted and shared by both subtiles.
// ---------------------------------------------------------------------------
__global__ __launch_bounds__(256) void attn_mfma_kernel(
    const unsigned short* __restrict__ qg,   // [B,H,S,D]
    const unsigned short* __restrict__ kg,   // [B,H,S,D]
    const unsigned short* __restrict__ vtg,  // [B,H,D,S]
    unsigned short* __restrict__ att)        // [B,S,E]
{
    __shared__ __align__(16) unsigned short Ks[64][72];
    __shared__ __align__(16) unsigned short VTs[64][72];
    __shared__ __align__(16) unsigned short Pq[128][72];

    const int tid  = threadIdx.x;
    const int w    = tid >> 6;
    const int l15  = tid & 15;
    const int quad = (tid >> 4) & 3;
    const int qb   = blockIdx.x;
    const int bh   = blockIdx.y;

    const unsigned short* qp = qg  + (size_t)bh * Sc * Dc;
    const unsigned short* kp = kg  + (size_t)bh * Sc * Dc;
    const unsigned short* vp = vtg + (size_t)bh * Dc * Sc;

    int qrow[2];
    shortx8 qf[2][2];
    #pragma unroll
    for (int qs = 0; qs < 2; ++qs) {
        qrow[qs] = qb * 128 + 32 * w + 16 * qs + l15;
        qf[qs][0] = *(const shortx8*)(qp + (size_t)qrow[qs] * Dc + 8 * quad);
        qf[qs][1] = *(const shortx8*)(qp + (size_t)qrow[qs] * Dc + 32 + 8 * quad);
    }

    floatx4 Oacc[2][4];
    #pragma unroll
    for (int qs = 0; qs < 2; ++qs)
        #pragma unroll
        for (int mt = 0; mt < 4; ++mt)
            #pragma unroll
            for (int e = 0; e < 4; ++e) Oacc[qs][mt][e] = 0.0f;
    float lsum[2] = {0.0f, 0.0f};

    const int srow = tid >> 3, schk = tid & 7;
    const float cexp = 0.125f * 1.442695041f;   // score scale * log2(e)

    for (int kt = 0; kt < Sc / 64; ++kt) {
        #pragma unroll
        for (int it = 0; it < 2; ++it) {
            int row = srow + 32 * it;
            *(shortx8*)&Ks[row][schk * 8] =
                *(const shortx8*)(kp + (size_t)(kt * 64 + row) * Dc + schk * 8);
            *(shortx8*)&VTs[row][schk * 8] =
                *(const shortx8*)(vp + (size_t)row * Sc + kt * 64 + schk * 8);
        }
        __syncthreads();

        // hoisted fragments, shared across both q-subtiles
        shortx8 kf[2][4], vf[2][4];
        #pragma unroll
        for (int ks = 0; ks < 2; ++ks)
            #pragma unroll
            for (int mt = 0; mt < 4; ++mt) {
                kf[ks][mt] = *(shortx8*)&Ks[16 * mt + l15][32 * ks + 8 * quad];
                vf[ks][mt] = *(shortx8*)&VTs[16 * mt + l15][32 * ks + 8 * quad];
            }

        #pragma unroll
        for (int qs = 0; qs < 2; ++qs) {
            // ST = K·Q^T : lane holds ST[s=16mt+4quad+r][q]
            floatx4 st[4];
            #pragma unroll
            for (int mt = 0; mt < 4; ++mt)
                #pragma unroll
                for (int e = 0; e < 4; ++e) st[mt][e] = 0.0f;
            #pragma unroll
            for (int ks = 0; ks < 2; ++ks)
                #pragma unroll
                for (int mt = 0; mt < 4; ++mt)
                    st[mt] = __builtin_amdgcn_mfma_f32_16x16x32_bf16(
                        kf[ks][mt], qf[qs][ks], st[mt], 0, 0, 0);

            // P = exp(s/8) with fixed max; accumulate per-lane partial sum
            float rs = 0.0f;
            #pragma unroll
            for (int mt = 0; mt < 4; ++mt) {
                float p0 = exp2_fast(st[mt][0] * cexp);
                float p1 = exp2_fast(st[mt][1] * cexp);
                float p2 = exp2_fast(st[mt][2] * cexp);
                float p3 = exp2_fast(st[mt][3] * cexp);
                rs += (p0 + p1) + (p2 + p3);
                unsigned short tmp[4] __attribute__((aligned(8)));
                tmp[0] = f2bf(p0); tmp[1] = f2bf(p1); tmp[2] = f2bf(p2); tmp[3] = f2bf(p3);
                *(uint2*)&Pq[32 * w + 16 * qs + l15][16 * mt + 4 * quad] = *(uint2*)tmp;
            }
            lsum[qs] += rs;

            // O^T += V^T · P^T  (Pq rows are wave-private: no barrier needed)
            #pragma unroll
            for (int ks = 0; ks < 2; ++ks) {
                shortx8 pf = *(shortx8*)&Pq[32 * w + 16 * qs + l15][32 * ks + 8 * quad];
                #pragma unroll
                for (int mt = 0; mt < 4; ++mt)
                    Oacc[qs][mt] = __builtin_amdgcn_mfma_f32_16x16x32_bf16(
                        vf[ks][mt], pf, Oacc[qs][mt], 0, 0, 0);
            }
        }
        __syncthreads();
    }

    // finalize: single l-reduction across quads, then store
    const int b = bh >> 4, hh = bh & 15;
    #pragma unroll
    for (int qs = 0; qs < 2; ++qs) {
        float l = lsum[qs];
        l += __shfl_xor(l, 16, 64);
        l += __shfl_xor(l, 32, 64);
        const float inv = 1.0f / l;
        #pragma unroll
        for (int mt = 0; mt < 4; ++mt) {
            unsigned short tmp[4] __attribute__((aligned(8)));
            #pragma unroll
            for (int r = 0; r < 4; ++r) tmp[r] = f2bf(Oacc[qs][mt][r] * inv);
            size_t base = ((size_t)b * Sc + qrow[qs]) * Ec + hh * 64 + 16 * mt + 4 * quad;
            *(uint2*)(att + base) = *(uint2*)tmp;
        }
    }
}

// ---------------------------------------------------------------------------
// Kernel 3: MFMA out-projection, 64x128 tile, out = att @ Wc^T + bc (fp32).
// 4 waves in 2x2 quadrants (32m x 64n each). Grid 64x8 = 512 blocks (2/CU).
// ---------------------------------------------------------------------------
__global__ __launch_bounds__(256) void outproj_mfma_kernel(
    const unsigned short* __restrict__ Ab,   // attb [4096,1024]
    const unsigned short* __restrict__ Wb,   // Wcb [1024,1024]
    const float* __restrict__ bias,
    float* __restrict__ out)                 // [4096,1024] fp32
{
    __shared__ __align__(16) unsigned short As[64][72];
    __shared__ __align__(16) unsigned short Ws[128][72];

    const int tid = threadIdx.x;
    const int w = tid >> 6, l15 = tid & 15, quad = (tid >> 4) & 3;
    const int wq = w >> 1, wn = w & 1;
    const int m0 = blockIdx.x * 64;
    const int n0 = blockIdx.y * 128;
    const int srow = tid >> 3, schk = tid & 7;

    floatx4 acc[2][4];
    #pragma unroll
    for (int ms = 0; ms < 2; ++ms)
        #pragma unroll
        for (int ns = 0; ns < 4; ++ns)
            #pragma unroll
            for (int e = 0; e < 4; ++e) acc[ms][ns][e] = 0.0f;

    for (int k0 = 0; k0 < Kdim; k0 += 64) {
        #pragma unroll
        for (int it = 0; it < 2; ++it) {
            int row = srow + 32 * it;
            *(shortx8*)&As[row][schk * 8] =
                *(const shortx8*)(Ab + (size_t)(m0 + row) * Kdim + k0 + schk * 8);
        }
        #pragma unroll
        for (int it = 0; it < 4; ++it) {
            int row = srow + 32 * it;
            *(shortx8*)&Ws[row][schk * 8] =
                *(const shortx8*)(Wb + (size_t)(n0 + row) * Kdim + k0 + schk * 8);
        }
        __syncthreads();
        #pragma unroll
        for (int ks = 0; ks < 2; ++ks) {
            shortx8 af[2], bf[4];
            #pragma unroll
            for (int ms = 0; ms < 2; ++ms)
                af[ms] = *(shortx8*)&As[32 * wq + 16 * ms + l15][32 * ks + 8 * quad];
            #pragma unroll
            for (int ns = 0; ns < 4; ++ns)
                bf[ns] = *(shortx8*)&Ws[64 * wn + 16 * ns + l15][32 * ks + 8 * quad];
            #pragma unroll
            for (int ms = 0; ms < 2; ++ms)
                #pragma unroll
                for (int ns = 0; ns < 4; ++ns)
                    acc[ms][ns] = __builtin_amdgcn_mfma_f32_16x16x32_bf16(
                        af[ms], bf[ns], acc[ms][ns], 0, 0, 0);
        }
        __syncthreads();
    }

    #pragma unroll
    for (int ns = 0; ns < 4; ++ns) {
        const float bv = bias[n0 + 64 * wn + 16 * ns + l15];
        #pragma unroll
        for (int ms = 0; ms < 2; ++ms)
            #pragma unroll
            for (int r = 0; r < 4; ++r) {
                int m = m0 + 32 * wq + 16 * ms + 4 * quad + r;
                out[(size_t)m * Kdim + n0 + 64 * wn + 16 * ns + l15] = acc[ms][ns][r] + bv;
            }
    }
}

// ---------------------------------------------------------------------------
extern "C" void kernel_launch(void* const* d_in, const int* in_sizes, int n_in,
                              void* d_out, int out_size, void* d_ws, size_t ws_size,
                              hipStream_t stream) {
    const float* x  = (const float*)d_in[0];
    const float* Wq = (const float*)d_in[1];
    const float* Wk = (const float*)d_in[2];
    const float* Wv = (const float*)d_in[3];
    const float* Wc = (const float*)d_in[4];
    const float* bc = (const float*)d_in[5];
    float* out = (float*)d_out;

    // bf16 workspace layout (bytes): xb 8M | Wqb/Wkb/Wvb/Wcb 2M ea | qb,kb 8M ea
    // | vtb 8M | attb 8M  => 48 MB total
    char* p = (char*)d_ws;
    unsigned short* xb   = (unsigned short*)(p);
    unsigned short* Wqb  = (unsigned short*)(p + (8u << 20));
    unsigned short* Wkb  = (unsigned short*)(p + (10u << 20));
    unsigned short* Wvb  = (unsigned short*)(p + (12u << 20));
    unsigned short* Wcb  = (unsigned short*)(p + (14u << 20));
    unsigned short* qb_  = (unsigned short*)(p + (16u << 20));
    unsigned short* kb_  = (unsigned short*)(p + (24u << 20));
    unsigned short* vtb  = (unsigned short*)(p + (32u << 20));
    unsigned short* attb = (unsigned short*)(p + (40u << 20));

    hipLaunchKernelGGL(convert_all_kernel, dim3(8192), dim3(256), 0, stream,
                       x, Wq, Wk, Wv, Wc, xb, Wqb, Wkb, Wvb, Wcb);

    hipLaunchKernelGGL(proj_mfma_kernel, dim3(Mrows / 128, Ec / 128, 3), dim3(256), 0, stream,
                       xb, Wqb, Wkb, Wvb, qb_, kb_, vtb);

    hipLaunchKernelGGL(attn_mfma_kernel, dim3(Sc / 128, Bc * Hc), dim3(256), 0, stream,
                       qb_, kb_, vtb, attb);

    hipLaunchKernelGGL(outproj_mfma_kernel, dim3(Mrows / 64, Ec / 128), dim3(256), 0, stream,
                       attb, Wcb, bc, out);
}

// Round 4
// 212.827 us; speedup vs baseline: 7.2221x; 1.0740x over previous
//
#include <hip/hip_runtime.h>
#include <hip/hip_bf16.h>

// Problem constants
constexpr int Bc = 2, Sc = 2048, Ec = 1024, Hc = 16, Dc = 64;
constexpr int Mrows = Bc * Sc;   // 4096
constexpr int Kdim  = Ec;        // 1024

typedef float  floatx4 __attribute__((ext_vector_type(4)));
typedef short  shortx8 __attribute__((ext_vector_type(8)));

__device__ inline unsigned short f2bf(float f) {
    union { __hip_bfloat16 h; unsigned short u; } cv;
    cv.h = __float2bfloat16(f);
    return cv.u;
}
__device__ inline float bf2f(unsigned short u) {
    union { unsigned int i; float f; } c; c.i = ((unsigned int)u) << 16; return c.f;
}
__device__ inline float exp2_fast(float x) {
#if __has_builtin(__builtin_amdgcn_exp2f)
    return __builtin_amdgcn_exp2f(x);
#else
    return __expf(x * 0.69314718056f);
#endif
}

// async global->LDS DMA, 16 B/lane; HW dest = wave-uniform base + lane*16.
__device__ __forceinline__ void gll16(const void* g, void* lds) {
    __builtin_amdgcn_global_load_lds(
        (const __attribute__((address_space(1))) void*)g,
        (__attribute__((address_space(3))) void*)lds, 16, 0, 0);
}

// ---------------------------------------------------------------------------
// Kernel 0: convert x, Wq, Wk, Wv, Wc (fp32) -> bf16 workspace
// ---------------------------------------------------------------------------
__global__ __launch_bounds__(256) void convert_all_kernel(
    const float* __restrict__ x,  const float* __restrict__ Wq,
    const float* __restrict__ Wk, const float* __restrict__ Wv,
    const float* __restrict__ Wc,
    unsigned short* __restrict__ xb,  unsigned short* __restrict__ Wqb,
    unsigned short* __restrict__ Wkb, unsigned short* __restrict__ Wvb,
    unsigned short* __restrict__ Wcb)
{
    const long t = (long)blockIdx.x * 256 + threadIdx.x;
    const long i = t * 4;
    const float* src; unsigned short* dst; long off;
    if (i < 4194304) { src = x; dst = xb; off = i; }
    else {
        long j = i - 4194304;
        int wsel = (int)(j >> 20);
        off = j & 1048575;
        src = (wsel == 0) ? Wq : (wsel == 1) ? Wk : (wsel == 2) ? Wv : Wc;
        dst = (wsel == 0) ? Wqb : (wsel == 1) ? Wkb : (wsel == 2) ? Wvb : Wcb;
    }
    float4 v = *(const float4*)(src + off);
    unsigned short tmp[4] __attribute__((aligned(8)));
    tmp[0] = f2bf(v.x); tmp[1] = f2bf(v.y); tmp[2] = f2bf(v.z); tmp[3] = f2bf(v.w);
    *(uint2*)(dst + off) = *(uint2*)tmp;
}

// ---------------------------------------------------------------------------
// Kernel 1: MFMA projection + quantum epilogue, 128x128 tile, async staging.
// Tiles are UNPADDED (row stride 128 B); global reads are chunk-swizzled
// (cg = c ^ (row&7)) so b128 fragment reads spread uniformly over banks.
// blockIdx.z selects {q,k,v}; z==2 writes V transposed [B,H,D,S].
// ---------------------------------------------------------------------------
__global__ __launch_bounds__(256) void proj_mfma_kernel(
    const unsigned short* __restrict__ Ab,   // x bf16 [4096,1024]
    const unsigned short* __restrict__ Wqb,
    const unsigned short* __restrict__ Wkb,
    const unsigned short* __restrict__ Wvb,
    unsigned short* __restrict__ oq,         // [B,H,S,D]
    unsigned short* __restrict__ ok,         // [B,H,S,D]
    unsigned short* __restrict__ ov)         // [B,H,D,S]
{
    __shared__ __align__(16) char smem[33792];   // As 16K | Ws 16K; Cs overlay 33792
    float (*Cs)[132] = (float(*)[132])smem;
    __shared__ float Sp[64][9];

    const int z = blockIdx.z;
    const unsigned short* Wb = (z == 0) ? Wqb : (z == 1) ? Wkb : Wvb;
    unsigned short* out      = (z == 0) ? oq  : (z == 1) ? ok  : ov;
    const int mode = (z == 2) ? 1 : 0;

    const int tid = threadIdx.x;
    const int lane = tid & 63;
    const int w = tid >> 6, l15 = tid & 15, quad = (tid >> 4) & 3;
    const int wq = w >> 1, wn = w & 1;
    const int m0 = blockIdx.x * 128;
    const int n0 = blockIdx.y * 128;
    const int h0 = n0 >> 6;
    const int sw = l15 & 7;

    floatx4 acc[4][4];
    #pragma unroll
    for (int ms = 0; ms < 4; ++ms)
        #pragma unroll
        for (int ns = 0; ns < 4; ++ns)
            #pragma unroll
            for (int e = 0; e < 4; ++e) acc[ms][ns][e] = 0.0f;

    for (int k0 = 0; k0 < Kdim; k0 += 64) {
        #pragma unroll
        for (int j = 0; j < 4; ++j) {
            int idx = j * 64 + lane;
            int row = 32 * w + (idx >> 3);
            int cg  = ((idx & 7) ^ (idx >> 3)) & 7;
            gll16(Ab + (size_t)(m0 + row) * Kdim + k0 + cg * 8,
                  smem + 4096 * w + 1024 * j);
            gll16(Wb + (size_t)(n0 + row) * Kdim + k0 + cg * 8,
                  smem + 16384 + 4096 * w + 1024 * j);
        }
        __syncthreads();
        #pragma unroll
        for (int ks = 0; ks < 2; ++ks) {
            shortx8 af[4], bf[4];
            #pragma unroll
            for (int ms = 0; ms < 4; ++ms)
                af[ms] = *(shortx8*)(smem + (64 * wq + 16 * ms + l15) * 128
                                     + (((4 * ks + quad) ^ sw) << 4));
            #pragma unroll
            for (int ns = 0; ns < 4; ++ns)
                bf[ns] = *(shortx8*)(smem + 16384 + (64 * wn + 16 * ns + l15) * 128
                                     + (((4 * ks + quad) ^ sw) << 4));
            #pragma unroll
            for (int ms = 0; ms < 4; ++ms)
                #pragma unroll
                for (int ns = 0; ns < 4; ++ns)
                    acc[ms][ns] = __builtin_amdgcn_mfma_f32_16x16x32_bf16(
                        af[ms], bf[ns], acc[ms][ns], 0, 0, 0);
        }
        __syncthreads();
    }

    const int b = m0 >> 11;
    const int sbase = m0 & (Sc - 1);

    // Epilogue: two 64-row passes (Cs overlays staging LDS; K-loop done)
    for (int pass = 0; pass < 2; ++pass) {
        if (wq == pass) {
            #pragma unroll
            for (int ms = 0; ms < 4; ++ms)
                #pragma unroll
                for (int ns = 0; ns < 4; ++ns)
                    #pragma unroll
                    for (int r = 0; r < 4; ++r)
                        Cs[16 * ms + 4 * quad + r][64 * wn + 16 * ns + l15] =
                            __cosf(acc[ms][ns][r]);
        }
        __syncthreads();
        #pragma unroll
        for (int t = tid; t < 512; t += 256) {
            int row = t >> 3, seg = t & 7;
            float pr = 1.0f;
            #pragma unroll
            for (int c = 0; c < 16; ++c) pr *= Cs[row][seg * 16 + c];
            Sp[row][seg] = pr;
        }
        __syncthreads();
        if (mode == 0) {
            #pragma unroll
            for (int t = tid; t < 512; t += 256) {
                int row = t >> 3, seg = t & 7;
                float p = 1.0f;
                for (int j = (seg & 4); j < seg; ++j) p *= Sp[row][j];
                unsigned short tmp[16] __attribute__((aligned(16)));
                #pragma unroll
                for (int c = 0; c < 16; ++c) { p *= Cs[row][seg * 16 + c]; tmp[c] = f2bf(p); }
                int h = h0 + (seg >> 2);
                int s = sbase + pass * 64 + row;
                size_t base = (((size_t)b * Hc + h) * Sc + s) * Dc + (seg & 3) * 16;
                *(shortx8*)(out + base)     = *(shortx8*)&tmp[0];
                *(shortx8*)(out + base + 8) = *(shortx8*)&tmp[8];
            }
            __syncthreads();
        } else {
            #pragma unroll
            for (int t = tid; t < 512; t += 256) {
                int row = t >> 3, seg = t & 7;
                float p = 1.0f;
                for (int j = (seg & 4); j < seg; ++j) p *= Sp[row][j];
                #pragma unroll
                for (int c = 0; c < 16; ++c) { p *= Cs[row][seg * 16 + c]; Cs[row][seg * 16 + c] = p; }
            }
            __syncthreads();
            #pragma unroll
            for (int t = tid; t < 512; t += 256) {
                int col = t >> 2, chunk = t & 3;
                int h = h0 + (col >> 6), d = col & 63;
                unsigned short tmp[16] __attribute__((aligned(16)));
                #pragma unroll
                for (int j = 0; j < 16; ++j) tmp[j] = f2bf(Cs[chunk * 16 + j][col]);
                size_t base = (((size_t)b * Hc + h) * Dc + d) * Sc
                              + sbase + pass * 64 + chunk * 16;
                *(shortx8*)(out + base)     = *(shortx8*)&tmp[0];
                *(shortx8*)(out + base + 8) = *(shortx8*)&tmp[8];
            }
            __syncthreads();
        }
    }
}

// ---------------------------------------------------------------------------
// Kernel 2: MFMA flash attention, QTILE=128, fixed-max softmax, S-SPLIT x2.
// Each block handles 16 of 32 K-tiles (blockIdx.y = half). Partials are
// plain sums (no max rescale): O_part bf16 [B,S,E] + l_part fp32, combined
// by combine_kernel. Async K/V staging into unpadded swizzled tiles.
// ---------------------------------------------------------------------------
__global__ __launch_bounds__(256) void attn_mfma_kernel(
    const unsigned short* __restrict__ qg,   // [B,H,S,D]
    const unsigned short* __restrict__ kg,   // [B,H,S,D]
    const unsigned short* __restrict__ vtg,  // [B,H,D,S]
    unsigned short* __restrict__ o1,         // partial O, half 0 [B,S,E]
    unsigned short* __restrict__ o2,         // partial O, half 1 [B,S,E]
    float* __restrict__ lpart)               // [2][B*H][S]
{
    __shared__ __align__(16) char smem[34816];   // Ks 8K | VTs 8K | Pq 18K
    unsigned short (*Pq)[72] = (unsigned short(*)[72])(smem + 16384);

    const int tid  = threadIdx.x;
    const int lane = tid & 63;
    const int w    = tid >> 6;
    const int l15  = tid & 15;
    const int quad = (tid >> 4) & 3;
    const int qb   = blockIdx.x;
    const int half = blockIdx.y;
    const int bh   = blockIdx.z;
    const int sw   = l15 & 7;

    const unsigned short* qp = qg  + (size_t)bh * Sc * Dc;
    const unsigned short* kp = kg  + (size_t)bh * Sc * Dc;
    const unsigned short* vp = vtg + (size_t)bh * Dc * Sc;

    int qrow[2];
    shortx8 qf[2][2];
    #pragma unroll
    for (int qs = 0; qs < 2; ++qs) {
        qrow[qs] = qb * 128 + 32 * w + 16 * qs + l15;
        qf[qs][0] = *(const shortx8*)(qp + (size_t)qrow[qs] * Dc + 8 * quad);
        qf[qs][1] = *(const shortx8*)(qp + (size_t)qrow[qs] * Dc + 32 + 8 * quad);
    }

    floatx4 Oacc[2][4];
    #pragma unroll
    for (int qs = 0; qs < 2; ++qs)
        #pragma unroll
        for (int mt = 0; mt < 4; ++mt)
            #pragma unroll
            for (int e = 0; e < 4; ++e) Oacc[qs][mt][e] = 0.0f;
    float lsum[2] = {0.0f, 0.0f};

    const float cexp = 0.125f * 1.442695041f;   // score scale * log2(e)

    for (int kt = half * 16; kt < half * 16 + 16; ++kt) {
        #pragma unroll
        for (int j = 0; j < 2; ++j) {
            int idx = j * 64 + lane;
            int row = 16 * w + (idx >> 3);
            int cg  = ((idx & 7) ^ (idx >> 3)) & 7;
            gll16(kp + (size_t)(kt * 64 + row) * Dc + cg * 8,
                  smem + 2048 * w + 1024 * j);
            gll16(vp + (size_t)row * Sc + kt * 64 + cg * 8,
                  smem + 8192 + 2048 * w + 1024 * j);
        }
        __syncthreads();

        shortx8 kf[2][4], vf[2][4];
        #pragma unroll
        for (int ks = 0; ks < 2; ++ks)
            #pragma unroll
            for (int mt = 0; mt < 4; ++mt) {
                int off = (16 * mt + l15) * 128 + (((4 * ks + quad) ^ sw) << 4);
                kf[ks][mt] = *(shortx8*)(smem + off);
                vf[ks][mt] = *(shortx8*)(smem + 8192 + off);
            }

        #pragma unroll
        for (int qs = 0; qs < 2; ++qs) {
            floatx4 st[4];
            #pragma unroll
            for (int mt = 0; mt < 4; ++mt)
                #pragma unroll
                for (int e = 0; e < 4; ++e) st[mt][e] = 0.0f;
            #pragma unroll
            for (int ks = 0; ks < 2; ++ks)
                #pragma unroll
                for (int mt = 0; mt < 4; ++mt)
                    st[mt] = __builtin_amdgcn_mfma_f32_16x16x32_bf16(
                        kf[ks][mt], qf[qs][ks], st[mt], 0, 0, 0);

            float rs = 0.0f;
            #pragma unroll
            for (int mt = 0; mt < 4; ++mt) {
                float p0 = exp2_fast(st[mt][0] * cexp);
                float p1 = exp2_fast(st[mt][1] * cexp);
                float p2 = exp2_fast(st[mt][2] * cexp);
                float p3 = exp2_fast(st[mt][3] * cexp);
                rs += (p0 + p1) + (p2 + p3);
                unsigned short tmp[4] __attribute__((aligned(8)));
                tmp[0] = f2bf(p0); tmp[1] = f2bf(p1); tmp[2] = f2bf(p2); tmp[3] = f2bf(p3);
                *(uint2*)&Pq[32 * w + 16 * qs + l15][16 * mt + 4 * quad] = *(uint2*)tmp;
            }
            lsum[qs] += rs;

            #pragma unroll
            for (int ks = 0; ks < 2; ++ks) {
                shortx8 pf = *(shortx8*)&Pq[32 * w + 16 * qs + l15][32 * ks + 8 * quad];
                #pragma unroll
                for (int mt = 0; mt < 4; ++mt)
                    Oacc[qs][mt] = __builtin_amdgcn_mfma_f32_16x16x32_bf16(
                        vf[ks][mt], pf, Oacc[qs][mt], 0, 0, 0);
            }
        }
        __syncthreads();
    }

    // store partial O (bf16, unnormalized) + partial l (fp32)
    const int b = bh >> 4, hh = bh & 15;
    unsigned short* opart = half ? o2 : o1;
    float* lp = lpart + ((size_t)half * (Bc * Hc) + bh) * Sc;
    #pragma unroll
    for (int qs = 0; qs < 2; ++qs) {
        float l = lsum[qs];
        l += __shfl_xor(l, 16, 64);
        l += __shfl_xor(l, 32, 64);
        if (quad == 0) lp[qrow[qs]] = l;
        #pragma unroll
        for (int mt = 0; mt < 4; ++mt) {
            unsigned short tmp[4] __attribute__((aligned(8)));
            #pragma unroll
            for (int r = 0; r < 4; ++r) tmp[r] = f2bf(Oacc[qs][mt][r]);
            size_t base = ((size_t)b * Sc + qrow[qs]) * Ec + hh * 64 + 16 * mt + 4 * quad;
            *(uint2*)(opart + base) = *(uint2*)tmp;
        }
    }
}

// ---------------------------------------------------------------------------
// Kernel 2b: combine halves: att = (O1 + O2) / (l1 + l2), in place into o1.
// ---------------------------------------------------------------------------
__global__ __launch_bounds__(256) void combine_kernel(
    unsigned short* __restrict__ o1,         // in/out (becomes att)
    const unsigned short* __restrict__ o2,
    const float* __restrict__ lpart)         // [2][B*H][S]
{
    const size_t t = (size_t)blockIdx.x * 256 + threadIdx.x;
    const size_t base = t * 8;
    const int e = (int)(base & (Ec - 1));
    const int h = e >> 6;
    const size_t bs = base >> 10;
    const int b = (int)(bs >> 11), s = (int)(bs & (Sc - 1));
    const int bh = b * Hc + h;
    const float l = lpart[(size_t)bh * Sc + s]
                  + lpart[(size_t)(Bc * Hc + bh) * Sc + s];
    const float inv = 1.0f / l;
    uint4 a = *(const uint4*)(o1 + base);
    uint4 c = *(const uint4*)(o2 + base);
    const unsigned short* ua = (const unsigned short*)&a;
    const unsigned short* uc = (const unsigned short*)&c;
    unsigned short r[8] __attribute__((aligned(16)));
    #pragma unroll
    for (int i = 0; i < 8; ++i)
        r[i] = f2bf((bf2f(ua[i]) + bf2f(uc[i])) * inv);
    *(uint4*)(o1 + base) = *(uint4*)r;
}

// ---------------------------------------------------------------------------
// Kernel 3: MFMA out-projection, 64x128 tile, async swizzled staging.
// ---------------------------------------------------------------------------
__global__ __launch_bounds__(256) void outproj_mfma_kernel(
    const unsigned short* __restrict__ Ab,   // attb [4096,1024]
    const unsigned short* __restrict__ Wb,   // Wcb [1024,1024]
    const float* __restrict__ bias,
    float* __restrict__ out)                 // [4096,1024] fp32
{
    __shared__ __align__(16) char smem[24576];   // As 8K | Ws 16K

    const int tid = threadIdx.x;
    const int lane = tid & 63;
    const int w = tid >> 6, l15 = tid & 15, quad = (tid >> 4) & 3;
    const int wq = w >> 1, wn = w & 1;
    const int m0 = blockIdx.x * 64;
    const int n0 = blockIdx.y * 128;
    const int sw = l15 & 7;

    floatx4 acc[2][4];
    #pragma unroll
    for (int ms = 0; ms < 2; ++ms)
        #pragma unroll
        for (int ns = 0; ns < 4; ++ns)
            #pragma unroll
            for (int e = 0; e < 4; ++e) acc[ms][ns][e] = 0.0f;

    for (int k0 = 0; k0 < Kdim; k0 += 64) {
        #pragma unroll
        for (int j = 0; j < 2; ++j) {
            int idx = j * 64 + lane;
            int row = 16 * w + (idx >> 3);
            int cg  = ((idx & 7) ^ (idx >> 3)) & 7;
            gll16(Ab + (size_t)(m0 + row) * Kdim + k0 + cg * 8,
                  smem + 2048 * w + 1024 * j);
        }
        #pragma unroll
        for (int j = 0; j < 4; ++j) {
            int idx = j * 64 + lane;
            int row = 32 * w + (idx >> 3);
            int cg  = ((idx & 7) ^ (idx >> 3)) & 7;
            gll16(Wb + (size_t)(n0 + row) * Kdim + k0 + cg * 8,
                  smem + 8192 + 4096 * w + 1024 * j);
        }
        __syncthreads();
        #pragma unroll
        for (int ks = 0; ks < 2; ++ks) {
            shortx8 af[2], bf[4];
            #pragma unroll
            for (int ms = 0; ms < 2; ++ms)
                af[ms] = *(shortx8*)(smem + (32 * wq + 16 * ms + l15) * 128
                                     + (((4 * ks + quad) ^ sw) << 4));
            #pragma unroll
            for (int ns = 0; ns < 4; ++ns)
                bf[ns] = *(shortx8*)(smem + 8192 + (64 * wn + 16 * ns + l15) * 128
                                     + (((4 * ks + quad) ^ sw) << 4));
            #pragma unroll
            for (int ms = 0; ms < 2; ++ms)
                #pragma unroll
                for (int ns = 0; ns < 4; ++ns)
                    acc[ms][ns] = __builtin_amdgcn_mfma_f32_16x16x32_bf16(
                        af[ms], bf[ns], acc[ms][ns], 0, 0, 0);
        }
        __syncthreads();
    }

    #pragma unroll
    for (int ns = 0; ns < 4; ++ns) {
        const float bv = bias[n0 + 64 * wn + 16 * ns + l15];
        #pragma unroll
        for (int ms = 0; ms < 2; ++ms)
            #pragma unroll
            for (int r = 0; r < 4; ++r) {
                int m = m0 + 32 * wq + 16 * ms + 4 * quad + r;
                out[(size_t)m * Kdim + n0 + 64 * wn + 16 * ns + l15] = acc[ms][ns][r] + bv;
            }
    }
}

// ---------------------------------------------------------------------------
extern "C" void kernel_launch(void* const* d_in, const int* in_sizes, int n_in,
                              void* d_out, int out_size, void* d_ws, size_t ws_size,
                              hipStream_t stream) {
    const float* x  = (const float*)d_in[0];
    const float* Wq = (const float*)d_in[1];
    const float* Wk = (const float*)d_in[2];
    const float* Wv = (const float*)d_in[3];
    const float* Wc = (const float*)d_in[4];
    const float* bc = (const float*)d_in[5];
    float* out = (float*)d_out;

    // ws layout (48 MB): xb 8M | Wqb/Wkb/Wvb/Wcb 2M ea | qb 8M | kb 8M | vtb 8M
    // | attb 8M.  After proj, xb region is reused as O2 partial and Wqb region
    // as lpart (both dead); attb region doubles as O1 partial (combined in place).
    char* p = (char*)d_ws;
    unsigned short* xb   = (unsigned short*)(p);
    unsigned short* Wqb  = (unsigned short*)(p + (8u << 20));
    unsigned short* Wkb  = (unsigned short*)(p + (10u << 20));
    unsigned short* Wvb  = (unsigned short*)(p + (12u << 20));
    unsigned short* Wcb  = (unsigned short*)(p + (14u << 20));
    unsigned short* qb_  = (unsigned short*)(p + (16u << 20));
    unsigned short* kb_  = (unsigned short*)(p + (24u << 20));
    unsigned short* vtb  = (unsigned short*)(p + (32u << 20));
    unsigned short* attb = (unsigned short*)(p + (40u << 20));
    unsigned short* o2b  = xb;                    // dead after proj
    float*          lpart = (float*)(p + (8u << 20));   // dead Wqb region

    hipLaunchKernelGGL(convert_all_kernel, dim3(8192), dim3(256), 0, stream,
                       x, Wq, Wk, Wv, Wc, xb, Wqb, Wkb, Wvb, Wcb);

    hipLaunchKernelGGL(proj_mfma_kernel, dim3(Mrows / 128, Ec / 128, 3), dim3(256), 0, stream,
                       xb, Wqb, Wkb, Wvb, qb_, kb_, vtb);

    hipLaunchKernelGGL(attn_mfma_kernel, dim3(Sc / 128, 2, Bc * Hc), dim3(256), 0, stream,
                       qb_, kb_, vtb, attb, o2b, lpart);

    hipLaunchKernelGGL(combine_kernel, dim3(Mrows * Ec / (256 * 8)), dim3(256), 0, stream,
                       attb, o2b, lpart);

    hipLaunchKernelGGL(outproj_mfma_kernel, dim3(Mrows / 64, Ec / 128), dim3(256), 0, stream,
                       attb, Wcb, bc, out);
}